// Round 14
// baseline (1182.613 us; speedup 1.0000x reference)
//
#include <hip/hip_runtime.h>

// BeitSelfAttention — f32 pipeline.
// R13 post-mortem: gemm bank-fix halved SQ_LDS_BANK_CONFLICT (1.1e7->5.5e6)
// but dur neutral -> store conflicts weren't critical-path. gemm frozen at
// best-known (518us).
// This round (loc_attn only): K-chunk LDS staging. QK^T's per-lane-row K
// gather (lane stride 256B) split every load into 64 L1 transactions
// (~41k/block, ~200us of TA processing). Now each 64-key chunk is staged
// cooperatively (coalesced) into transposed Kt[64][64]; QK reads Kt[d][lane]
// (bank=lane&31, 2-way=free). LDS 27.7->44.1KB (3 blocks/CU) + 2 barriers/
// chunk — accepted: removes the latency source instead of hiding it.
// PV's V loads stay global (already lane-contiguous/coalesced).
// cls_attn verbatim.
// Shapes: B=8 S=1569 D=768 NH=12 DH=64 NCLS=1 BS=49 M=32 NKV=6

#define S_TOT   1569
#define NBATCH  8

// -------- gemm_f32: QKV = X(nTok x 768) @ [Wq|Wk|Wv](768 x 2304) + bias
__global__ __launch_bounds__(256) void gemm_f32(const float* __restrict__ hs,
                                                const float* __restrict__ Wq,
                                                const float* __restrict__ Wk,
                                                const float* __restrict__ Wv,
                                                const float* __restrict__ bq,
                                                const float* __restrict__ bv,
                                                float* __restrict__ Q,
                                                float* __restrict__ K,
                                                float* __restrict__ V,
                                                int b0, int nTok) {
    __shared__ float As[128][20];   // [t][swizzled k]: 16 k + 4 pad
    __shared__ float Bs[16][136];   // [k][n]: 128 n + 8 pad
    int tid = threadIdx.x;
    int t0 = blockIdx.x * 128;
    int n0 = blockIdx.y * 128;
    int which = n0 / 768;
    int ng0 = n0 - which * 768;
    const float* W = (which == 0) ? Wq : (which == 1 ? Wk : Wv);
    const float* Xb = hs + (size_t)b0 * S_TOT * 768;

    int tr = tid >> 4;              // 0..15: rows tr*8 .. tr*8+7
    int tc = tid & 15;              // cols tc*4..+4 and 64+tc*4..+4

    int sat = tid >> 2;             // 0..63 (+0 / +64 halves)
    int sac4 = (tid & 3) * 4;       // k offset 0,4,8,12
    int sbk = tid >> 4;             // 0..15
    int sbn = (tid & 15) * 4;       // 0..60 (+0 / +64 halves)

    int scg = ((tid & 3) ^ ((sat >> 3) & 3)) * 4;
    int rswz = (tr & 3);            // read-side swizzle key

    int ta0 = t0 + sat;       if (ta0 >= nTok) ta0 = nTok - 1;
    int ta1 = t0 + sat + 64;  if (ta1 >= nTok) ta1 = nTok - 1;

    float acc[8][8];
#pragma unroll
    for (int i = 0; i < 8; i++)
#pragma unroll
        for (int j = 0; j < 8; j++) acc[i][j] = 0.f;

    // ---- prologue: prefetch tile 0 into registers
    float4 pa0, pa1, pb0, pb1;
    {
        pa0 = *(const float4*)(Xb + (size_t)ta0 * 768 + 0 + sac4);
        pa1 = *(const float4*)(Xb + (size_t)ta1 * 768 + 0 + sac4);
        const float* wr_ = W + (size_t)(0 + sbk) * 768 + ng0;
        pb0 = *(const float4*)(wr_ + sbn);
        pb1 = *(const float4*)(wr_ + 64 + sbn);
    }

    for (int k0 = 0; k0 < 768; k0 += 16) {
        // ---- write prefetched tile to LDS
        *(float4*)&As[sat][scg]      = pa0;
        *(float4*)&As[sat + 64][scg] = pa1;
        *(float4*)&Bs[sbk][sbn]      = pb0;
        *(float4*)&Bs[sbk][64 + sbn] = pb1;
        __syncthreads();

        // ---- issue next tile's loads (consumed next iteration)
        if (k0 + 16 < 768) {
            int kn = k0 + 16;
            pa0 = *(const float4*)(Xb + (size_t)ta0 * 768 + kn + sac4);
            pa1 = *(const float4*)(Xb + (size_t)ta1 * 768 + kn + sac4);
            const float* wr_ = W + (size_t)(kn + sbk) * 768 + ng0;
            pb0 = *(const float4*)(wr_ + sbn);
            pb1 = *(const float4*)(wr_ + 64 + sbn);
        }

        // ---- compute on current LDS tile
#pragma unroll
        for (int kq = 0; kq < 4; kq++) {
            float4 xa[8];
            int rc = (kq ^ rswz) * 4;           // swizzled read col-group
#pragma unroll
            for (int i = 0; i < 8; i++)
                xa[i] = *(const float4*)&As[tr * 8 + i][rc];
#pragma unroll
            for (int kk = 0; kk < 4; kk++) {
                int k = kq * 4 + kk;
                float4 w0 = *(const float4*)&Bs[k][tc * 4];
                float4 w1 = *(const float4*)&Bs[k][64 + tc * 4];
#pragma unroll
                for (int i = 0; i < 8; i++) {
                    float a = (kk == 0) ? xa[i].x : (kk == 1) ? xa[i].y
                            : (kk == 2) ? xa[i].z : xa[i].w;
                    acc[i][0] = fmaf(a, w0.x, acc[i][0]);
                    acc[i][1] = fmaf(a, w0.y, acc[i][1]);
                    acc[i][2] = fmaf(a, w0.z, acc[i][2]);
                    acc[i][3] = fmaf(a, w0.w, acc[i][3]);
                    acc[i][4] = fmaf(a, w1.x, acc[i][4]);
                    acc[i][5] = fmaf(a, w1.y, acc[i][5]);
                    acc[i][6] = fmaf(a, w1.z, acc[i][6]);
                    acc[i][7] = fmaf(a, w1.w, acc[i][7]);
                }
            }
        }
        __syncthreads();
    }

    float* dst = (which == 0) ? Q : (which == 1 ? K : V);
    const float* bias = (which == 0) ? bq : (which == 2 ? bv : nullptr);
#pragma unroll
    for (int hh = 0; hh < 2; hh++) {
        int nn = ng0 + hh * 64 + tc * 4;        // 0..767, multiple of 4
        int h = nn >> 6, d = nn & 63;
        float4 bv4 = make_float4(0.f, 0.f, 0.f, 0.f);
        if (bias) bv4 = *(const float4*)(bias + nn);
#pragma unroll
        for (int i = 0; i < 8; i++) {
            int t = t0 + tr * 8 + i;
            if (t >= nTok) continue;
            int bl = t / S_TOT;
            int s = t - bl * S_TOT;
            float4 o;
            o.x = acc[i][hh * 4 + 0] + bv4.x;
            o.y = acc[i][hh * 4 + 1] + bv4.y;
            o.z = acc[i][hh * 4 + 2] + bv4.z;
            o.w = acc[i][hh * 4 + 3] + bv4.w;
            *(float4*)(dst + ((size_t)(bl * 12 + h) * S_TOT + s) * 64 + d) = o;
        }
    }
}

// -------- cls attention (unchanged)
__global__ __launch_bounds__(256) void cls_attn(const float* __restrict__ Q,
                                                const float* __restrict__ K,
                                                const float* __restrict__ V,
                                                const float* __restrict__ rel,
                                                const int* __restrict__ rpi,
                                                float* __restrict__ out, int b0) {
    int bh = blockIdx.x;
    int bl = bh / 12, h = bh - bl * 12;
    __shared__ float p[S_TOT];
    __shared__ float4 qs4[16];
    __shared__ float red[256];
    __shared__ float wred[8];
    int tid = threadIdx.x, lane = tid & 63, w = tid >> 6;
    size_t base = (size_t)bh * S_TOT * 64;
    const float* Qb = Q + base;
    const float* Kb = K + base;
    const float* Vb = V + base;
    if (tid < 64) ((float*)qs4)[tid] = Qb[tid];
    __syncthreads();

    float lmx = -1e30f;
    for (int j = tid; j < S_TOT; j += 256) {
        const float4* kr = (const float4*)(Kb + j * 64);
        float a = 0.f;
#pragma unroll
        for (int d4 = 0; d4 < 16; d4++) {
            float4 kv = kr[d4];
            float4 qv = qs4[d4];
            a = fmaf(qv.x, kv.x, a); a = fmaf(qv.y, kv.y, a);
            a = fmaf(qv.z, kv.z, a); a = fmaf(qv.w, kv.w, a);
        }
        a = a * 0.125f + rel[rpi[j] * 12 + h];
        p[j] = a;
        lmx = fmaxf(lmx, a);
    }
#pragma unroll
    for (int off = 32; off > 0; off >>= 1) lmx = fmaxf(lmx, __shfl_xor(lmx, off));
    if (lane == 0) wred[w] = lmx;
    __syncthreads();
    float mx = fmaxf(fmaxf(wred[0], wred[1]), fmaxf(wred[2], wred[3]));
    float lsum = 0.f;
    for (int j = tid; j < S_TOT; j += 256) {
        float e = __expf(p[j] - mx);
        p[j] = e;
        lsum += e;
    }
#pragma unroll
    for (int off = 32; off > 0; off >>= 1) lsum += __shfl_xor(lsum, off);
    if (lane == 0) wred[4 + w] = lsum;
    __syncthreads();
    float inv = 1.0f / (wred[4] + wred[5] + wred[6] + wred[7]);
    float acc = 0.f;
    for (int j = w; j < S_TOT; j += 4) acc = fmaf(p[j], Vb[j * 64 + lane], acc);
    red[w * 64 + lane] = acc;
    __syncthreads();
    if (w == 0) {
        float o = (red[lane] + red[64 + lane] + red[128 + lane] + red[192 + lane]) * inv;
        out[(size_t)(b0 + bl) * S_TOT * 768 + h * 64 + lane] = o;
    }
}

// -------- block-sparse local attention — flash loop, XCD-swizzled,
// arithmetic bias index, no-max softmax, de-spilled, K-chunk LDS staging
// (this round): Kt[64][64] transposed, coalesced stage, conflict-free reads.
__global__ __launch_bounds__(256, 4) void loc_attn(const float* __restrict__ Q,
                                                   const float* __restrict__ K,
                                                   const float* __restrict__ V,
                                                   const float* __restrict__ rel,
                                                   const int* __restrict__ rand_idx,
                                                   float* __restrict__ out,
                                                   int b0, int ng) {
    // ---- XCD-contiguous decode (total = 32*ng divisible by 8, ng=12*cb)
    int d = blockIdx.x;
    int xcd = d & 7, kk_ = d >> 3;
    int slot = xcd * (ng << 2) + kk_;      // ng*4 = total/8 blocks per XCD
    int g = slot >> 5;                      // group = h + 12*bl
    int m = slot & 31;
    int h = g % 12;
    int bl = g / 12;

    __shared__ float Qlds[49][64];          // 12544 B
    __shared__ float Plds[4][13][64];       // 13312 B
    __shared__ float Kt[64][64];            // 16384 B (transposed K chunk)
    __shared__ float flds[4][13][5];        //  1040 B (per-chunk softmax sums)
    __shared__ int   cqlds[52];             //   208 B (per-row packed q coords)
    __shared__ unsigned short tok[320];     //   640 B   (total 44128)
    int tid = threadIdx.x, lane = tid & 63, w = tid >> 6;

    size_t base = (size_t)((bl * 12 + h) * S_TOT) * 64;
    const float* Qb = Q + base;
    const float* Kb = K + base;
    const float* Vb = V + base;

    // stage token table (295 entries, pad to 320 with token 0)
    for (int jj = tid; jj < 320; jj += 256) {
        int t = 0;
        if (jj >= 1 && jj < 295) {
            int j1 = jj - 1;
            int n = j1 / 49;
            int q = j1 - n * 49;
            int a;
            if (n == 0)      a = (m + 31) & 31;
            else if (n == 1) a = m;
            else if (n == 2) a = (m + 1) & 31;
            else             a = rand_idx[m * 3 + (n - 3)];
            t = 1 + a * 49 + q;
        }
        tok[jj] = (unsigned short)t;
    }
    // stage per-row packed query coords: cq = zq*729 + yq*27 + xq
    if (tid < 52) {
        int qr = 1 + m * 49 + tid;
        if (qr > S_TOT - 1) qr = S_TOT - 1;
        int pq = qr - 1;
        int zq = pq / 196;
        int rem = pq - zq * 196;
        int yq = rem / 14;
        int xq = rem - yq * 14;
        cqlds[tid] = zq * 729 + yq * 27 + xq;
    }
    // stage Q tile (49 rows), coalesced
    for (int idx = tid; idx < 49 * 64; idx += 256) {
        int r = idx >> 6, c = idx & 63;
        ((float*)Qlds)[idx] = Qb[(size_t)(1 + m * 49 + r) * 64 + c];
    }
    __syncthreads();

    float facc[13];
#pragma unroll
    for (int r = 0; r < 13; r++) facc[r] = 0.f;

    // staging role: thread handles row = tid>>2, cols cg*16..cg*16+15
    int srow = tid >> 2;
    int scg16 = (tid & 3) * 16;

    for (int jc = 0; jc < 5; jc++) {
        // ---- stage K chunk -> Kt (transposed), coalesced global reads
        __syncthreads();    // Kt free: all QK reads of previous chunk done
        {
            int t = tok[jc * 64 + srow];
            const float* kr = Kb + (size_t)t * 64 + scg16;
#pragma unroll
            for (int k4 = 0; k4 < 4; k4++) {
                float4 kv = *(const float4*)(kr + k4 * 4);
                int c = scg16 + k4 * 4;
                Kt[c + 0][srow] = kv.x;
                Kt[c + 1][srow] = kv.y;
                Kt[c + 2][srow] = kv.z;
                Kt[c + 3][srow] = kv.w;
            }
        }
        __syncthreads();

        int j = jc * 64 + lane;
        int tj = tok[j];

        // per-lane key coords -> bias offset  bidx = cq[i] + cjb
        int pj = tj - 1;
        int zj = pj / 196;
        int remj = pj - zj * 196;
        int yj = remj / 14;
        int xj = remj - yj * 14;
        int cjb = 5467 - (zj * 729 + yj * 27 + xj);
        bool iscls = (tj == 0);
        bool jv = j < 295;

        // ---- QK^T + bias + exp + sum, two row-passes (s[] stays 7 wide);
        //      K now from Kt[d][lane] (bank=lane&31 -> conflict-free)
#pragma unroll
        for (int half = 0; half < 2; half++) {
            const int r0 = half * 7;
            const int RN = half ? 6 : 7;
            float s[7];
#pragma unroll
            for (int rr = 0; rr < 7; rr++) s[rr] = 0.f;
#pragma unroll 4
            for (int d4 = 0; d4 < 16; d4++) {
                float k0v = Kt[d4 * 4 + 0][lane];
                float k1v = Kt[d4 * 4 + 1][lane];
                float k2v = Kt[d4 * 4 + 2][lane];
                float k3v = Kt[d4 * 4 + 3][lane];
#pragma unroll
                for (int rr = 0; rr < RN; rr++) {
                    int qrow = w + 4 * (r0 + rr);
                    if (qrow > 48) qrow = 48;       // pad rows (unused lanes)
                    float4 qv = *(const float4*)&Qlds[qrow][d4 * 4];   // broadcast
                    s[rr] = fmaf(qv.x, k0v, s[rr]);
                    s[rr] = fmaf(qv.y, k1v, s[rr]);
                    s[rr] = fmaf(qv.z, k2v, s[rr]);
                    s[rr] = fmaf(qv.w, k3v, s[rr]);
                }
            }
#pragma unroll
            for (int rr = 0; rr < RN; rr++) {
                int r = r0 + rr;
                int i = w + 4 * r;
                int ii = (i > 48) ? 48 : i;
                int bidx = iscls ? 10936 : (cqlds[ii] + cjb);
                float e = jv ? __expf(fmaf(s[rr], 0.125f, rel[bidx * 12 + h])) : 0.f;
                float ps = e;
#pragma unroll
                for (int off = 32; off > 0; off >>= 1) ps += __shfl_xor(ps, off);
                if (lane == 0) flds[w][r][jc] = ps;
                Plds[w][r][lane] = e;
            }
        }

        // ---- PV for this chunk: 4 keys per step, P via b128 broadcast,
        //      V loads lane-contiguous (coalesced) from global
#pragma unroll 4
        for (int jg = 0; jg < 16; jg++) {
            int jb = jc * 64 + jg * 4;
            int t0 = tok[jb + 0], t1 = tok[jb + 1], t2 = tok[jb + 2], t3 = tok[jb + 3];
            float v0 = Vb[(size_t)t0 * 64 + lane];
            float v1 = Vb[(size_t)t1 * 64 + lane];
            float v2 = Vb[(size_t)t2 * 64 + lane];
            float v3 = Vb[(size_t)t3 * 64 + lane];
#pragma unroll
            for (int r = 0; r < 13; r++) {
                float4 p4 = *(const float4*)&Plds[w][r][jg * 4];        // broadcast
                facc[r] = fmaf(p4.x, v0, facc[r]);
                facc[r] = fmaf(p4.y, v1, facc[r]);
                facc[r] = fmaf(p4.z, v2, facc[r]);
                facc[r] = fmaf(p4.w, v3, facc[r]);
            }
        }
    }

    // ---- epilogue: normalize (fl = sum of per-chunk partials) and store
    int nrows = (w == 0) ? 13 : 12;
    for (int r = 0; r < nrows; r++) {
        float fl = ((flds[w][r][0] + flds[w][r][1]) + (flds[w][r][2] + flds[w][r][3]))
                 + flds[w][r][4];
        int i = w + 4 * r;
        int st = 1 + m * 49 + i;
        out[((size_t)(b0 + bl) * S_TOT + st) * 768 + h * 64 + lane] = facc[r] / fl;
    }
}

extern "C" void kernel_launch(void* const* d_in, const int* in_sizes, int n_in,
                              void* d_out, int out_size, void* d_ws, size_t ws_size,
                              hipStream_t stream) {
    (void)in_sizes; (void)n_in; (void)out_size;
    const float* hs  = (const float*)d_in[0];
    const float* Wq  = (const float*)d_in[1];
    const float* bq  = (const float*)d_in[2];
    const float* Wk  = (const float*)d_in[3];
    const float* Wv  = (const float*)d_in[4];
    const float* bv  = (const float*)d_in[5];
    const float* rel = (const float*)d_in[6];
    const int*   rpi = (const int*)d_in[7];
    const int*   rnd = (const int*)d_in[8];
    float* out = (float*)d_out;
    char* ws = (char*)d_ws;

    // ws layout: Q | K | V  (each C * PBUF bytes)
    constexpr size_t PBUF = (size_t)12 * S_TOT * 64 * 4;     // 4,819,968 per batch

    int C = 1;
    if (ws_size >= 3 * PBUF) {
        size_t c = ws_size / (3 * PBUF);
        C = (c >= NBATCH) ? NBATCH : (int)c;
        if (C < 1) C = 1;
    }
    float* Q = (float*)(ws);
    float* K = (float*)(ws + (size_t)C * PBUF);
    float* V = (float*)(ws + (size_t)C * PBUF * 2);

    for (int b0 = 0; b0 < NBATCH; b0 += C) {
        int cb = (NBATCH - b0 < C) ? (NBATCH - b0) : C;
        int nTok = cb * S_TOT;
        gemm_f32<<<dim3((nTok + 127) / 128, 18), dim3(256), 0, stream>>>(
            hs, Wq, Wk, Wv, bq, bv, Q, K, V, b0, nTok);
        cls_attn<<<dim3(12 * cb), dim3(256), 0, stream>>>(Q, K, V, rel, rpi, out, b0);
        int ngrp = 12 * cb;
        loc_attn<<<dim3(32 * ngrp), dim3(256), 0, stream>>>(
            Q, K, V, rel, rnd, out, b0, ngrp);
    }
}

// Round 15
// 1088.457 us; speedup vs baseline: 1.0865x; 1.0865x over previous
//
#include <hip/hip_runtime.h>

// BeitSelfAttention — f32 pipeline.
// R14 post-mortem: Kt staging NEUTRAL (predicted 330-390, got ~505) ->
// reverted to R13 loc body. New finding: gemm's 1782-block grid vs 1536
// resident slots (6/CU) leaves a 246-block straggler round (~15-20% waste,
// explains Occupancy 29%).
// This round:
//  gemm_f32: PERSISTENT grid (1536 blocks, tile += gridDim.x over 99x18
//    tiles, tile=tx*18+ty for A-panel L2 locality). Body unchanged.
//  attn_fused: cls_attn merged into loc_attn launch (role by blockIdx,
//    union LDS = max 27.7KB) — removes serial ~50us cls + one launch gap;
//    outputs disjoint (cls: token 0, loc: tokens >=1).
// Shapes: B=8 S=1569 D=768 NH=12 DH=64 NCLS=1 BS=49 M=32 NKV=6

#define S_TOT   1569
#define NBATCH  8

// -------- gemm_f32: QKV = X(nTok x 768) @ [Wq|Wk|Wv](768 x 2304) + bias
// persistent: grid = min(1536, ntiles); block loops tiles strided.
__global__ __launch_bounds__(256) void gemm_f32(const float* __restrict__ hs,
                                                const float* __restrict__ Wq,
                                                const float* __restrict__ Wk,
                                                const float* __restrict__ Wv,
                                                const float* __restrict__ bq,
                                                const float* __restrict__ bv,
                                                float* __restrict__ Q,
                                                float* __restrict__ K,
                                                float* __restrict__ V,
                                                int b0, int nTok) {
    __shared__ float As[128][20];   // [t][swizzled k]: 16 k + 4 pad
    __shared__ float Bs[16][136];   // [k][n]: 128 n + 8 pad
    int tid = threadIdx.x;
    const float* Xb = hs + (size_t)b0 * S_TOT * 768;

    int tr = tid >> 4;              // 0..15: rows tr*8 .. tr*8+7
    int tc = tid & 15;              // cols tc*4..+4 and 64+tc*4..+4

    int sat = tid >> 2;             // 0..63 (+0 / +64 halves)
    int sac4 = (tid & 3) * 4;       // k offset 0,4,8,12
    int sbk = tid >> 4;             // 0..15
    int sbn = (tid & 15) * 4;       // 0..60 (+0 / +64 halves)

    int scg = ((tid & 3) ^ ((sat >> 3) & 3)) * 4;
    int rswz = (tr & 3);            // read-side swizzle key

    int ntt = (nTok + 127) >> 7;    // token tiles
    int ntiles = ntt * 18;

    for (int tile = blockIdx.x; tile < ntiles; tile += gridDim.x) {
        int tx = tile / 18;
        int ty = tile - tx * 18;
        int t0 = tx << 7;
        int n0 = ty << 7;
        int which = n0 / 768;
        int ng0 = n0 - which * 768;
        const float* W = (which == 0) ? Wq : (which == 1 ? Wk : Wv);

        int ta0 = t0 + sat;       if (ta0 >= nTok) ta0 = nTok - 1;
        int ta1 = t0 + sat + 64;  if (ta1 >= nTok) ta1 = nTok - 1;

        float acc[8][8];
#pragma unroll
        for (int i = 0; i < 8; i++)
#pragma unroll
            for (int j = 0; j < 8; j++) acc[i][j] = 0.f;

        // ---- prologue: prefetch tile 0 into registers
        float4 pa0, pa1, pb0, pb1;
        {
            pa0 = *(const float4*)(Xb + (size_t)ta0 * 768 + 0 + sac4);
            pa1 = *(const float4*)(Xb + (size_t)ta1 * 768 + 0 + sac4);
            const float* wr_ = W + (size_t)(0 + sbk) * 768 + ng0;
            pb0 = *(const float4*)(wr_ + sbn);
            pb1 = *(const float4*)(wr_ + 64 + sbn);
        }

        for (int k0 = 0; k0 < 768; k0 += 16) {
            // ---- write prefetched tile to LDS
            *(float4*)&As[sat][scg]      = pa0;
            *(float4*)&As[sat + 64][scg] = pa1;
            *(float4*)&Bs[sbk][sbn]      = pb0;
            *(float4*)&Bs[sbk][64 + sbn] = pb1;
            __syncthreads();

            // ---- issue next tile's loads (consumed next iteration)
            if (k0 + 16 < 768) {
                int kn = k0 + 16;
                pa0 = *(const float4*)(Xb + (size_t)ta0 * 768 + kn + sac4);
                pa1 = *(const float4*)(Xb + (size_t)ta1 * 768 + kn + sac4);
                const float* wr_ = W + (size_t)(kn + sbk) * 768 + ng0;
                pb0 = *(const float4*)(wr_ + sbn);
                pb1 = *(const float4*)(wr_ + 64 + sbn);
            }

            // ---- compute on current LDS tile
#pragma unroll
            for (int kq = 0; kq < 4; kq++) {
                float4 xa[8];
                int rc = (kq ^ rswz) * 4;           // swizzled read col-group
#pragma unroll
                for (int i = 0; i < 8; i++)
                    xa[i] = *(const float4*)&As[tr * 8 + i][rc];
#pragma unroll
                for (int kk = 0; kk < 4; kk++) {
                    int k = kq * 4 + kk;
                    float4 w0 = *(const float4*)&Bs[k][tc * 4];
                    float4 w1 = *(const float4*)&Bs[k][64 + tc * 4];
#pragma unroll
                    for (int i = 0; i < 8; i++) {
                        float a = (kk == 0) ? xa[i].x : (kk == 1) ? xa[i].y
                                : (kk == 2) ? xa[i].z : xa[i].w;
                        acc[i][0] = fmaf(a, w0.x, acc[i][0]);
                        acc[i][1] = fmaf(a, w0.y, acc[i][1]);
                        acc[i][2] = fmaf(a, w0.z, acc[i][2]);
                        acc[i][3] = fmaf(a, w0.w, acc[i][3]);
                        acc[i][4] = fmaf(a, w1.x, acc[i][4]);
                        acc[i][5] = fmaf(a, w1.y, acc[i][5]);
                        acc[i][6] = fmaf(a, w1.z, acc[i][6]);
                        acc[i][7] = fmaf(a, w1.w, acc[i][7]);
                    }
                }
            }
            __syncthreads();
        }

        float* dst = (which == 0) ? Q : (which == 1 ? K : V);
        const float* bias = (which == 0) ? bq : (which == 2 ? bv : nullptr);
#pragma unroll
        for (int hh = 0; hh < 2; hh++) {
            int nn = ng0 + hh * 64 + tc * 4;        // 0..767, multiple of 4
            int h = nn >> 6, d = nn & 63;
            float4 bv4 = make_float4(0.f, 0.f, 0.f, 0.f);
            if (bias) bv4 = *(const float4*)(bias + nn);
#pragma unroll
            for (int i = 0; i < 8; i++) {
                int t = t0 + tr * 8 + i;
                if (t >= nTok) continue;
                int bl = t / S_TOT;
                int s = t - bl * S_TOT;
                float4 o;
                o.x = acc[i][hh * 4 + 0] + bv4.x;
                o.y = acc[i][hh * 4 + 1] + bv4.y;
                o.z = acc[i][hh * 4 + 2] + bv4.z;
                o.w = acc[i][hh * 4 + 3] + bv4.w;
                *(float4*)(dst + ((size_t)(bl * 12 + h) * S_TOT + s) * 64 + d) = o;
            }
        }
    }
}

// -------- fused attention: blocks [0, 32*ng) = loc role (R13 body verbatim),
// blocks [32*ng, 33*ng) = cls role. Union LDS (27.7KB = max, not sum).
struct LocS {
    float Qlds[49][64];          // 12544 B
    float Plds[4][13][64];       // 13312 B
    float flds[4][13][5];        //  1040 B
    int   cqlds[52];             //   208 B
    unsigned short tok[320];     //   640 B
};
struct ClsS {
    float4 qs4[16];              //   256 B
    float  p[S_TOT];             //  6276 B
    float  red[256];             //  1024 B
    float  wred[8];              //    32 B
};
union SMem { LocS loc; ClsS cls; };

__global__ __launch_bounds__(256, 4) void attn_fused(const float* __restrict__ Q,
                                                     const float* __restrict__ K,
                                                     const float* __restrict__ V,
                                                     const float* __restrict__ rel,
                                                     const int* __restrict__ rpi,
                                                     const int* __restrict__ rand_idx,
                                                     float* __restrict__ out,
                                                     int b0, int ng) {
    __shared__ SMem sm;
    int tid = threadIdx.x, lane = tid & 63, w = tid >> 6;
    int dd = blockIdx.x;

    if (dd >= 32 * ng) {
        // ================= cls role =================
        int bh = dd - 32 * ng;
        int bl = bh / 12, h = bh - bl * 12;
        size_t base = (size_t)bh * S_TOT * 64;
        const float* Qb = Q + base;
        const float* Kb = K + base;
        const float* Vb = V + base;
        if (tid < 64) ((float*)sm.cls.qs4)[tid] = Qb[tid];
        __syncthreads();

        float lmx = -1e30f;
        for (int j = tid; j < S_TOT; j += 256) {
            const float4* kr = (const float4*)(Kb + j * 64);
            float a = 0.f;
#pragma unroll
            for (int d4 = 0; d4 < 16; d4++) {
                float4 kv = kr[d4];
                float4 qv = sm.cls.qs4[d4];
                a = fmaf(qv.x, kv.x, a); a = fmaf(qv.y, kv.y, a);
                a = fmaf(qv.z, kv.z, a); a = fmaf(qv.w, kv.w, a);
            }
            a = a * 0.125f + rel[rpi[j] * 12 + h];
            sm.cls.p[j] = a;
            lmx = fmaxf(lmx, a);
        }
#pragma unroll
        for (int off = 32; off > 0; off >>= 1) lmx = fmaxf(lmx, __shfl_xor(lmx, off));
        if (lane == 0) sm.cls.wred[w] = lmx;
        __syncthreads();
        float mx = fmaxf(fmaxf(sm.cls.wred[0], sm.cls.wred[1]),
                         fmaxf(sm.cls.wred[2], sm.cls.wred[3]));
        float lsum = 0.f;
        for (int j = tid; j < S_TOT; j += 256) {
            float e = __expf(sm.cls.p[j] - mx);
            sm.cls.p[j] = e;
            lsum += e;
        }
#pragma unroll
        for (int off = 32; off > 0; off >>= 1) lsum += __shfl_xor(lsum, off);
        if (lane == 0) sm.cls.wred[4 + w] = lsum;
        __syncthreads();
        float inv = 1.0f / (sm.cls.wred[4] + sm.cls.wred[5] + sm.cls.wred[6] + sm.cls.wred[7]);
        float acc = 0.f;
        for (int j = w; j < S_TOT; j += 4) acc = fmaf(sm.cls.p[j], Vb[j * 64 + lane], acc);
        sm.cls.red[w * 64 + lane] = acc;
        __syncthreads();
        if (w == 0) {
            float o = (sm.cls.red[lane] + sm.cls.red[64 + lane] +
                       sm.cls.red[128 + lane] + sm.cls.red[192 + lane]) * inv;
            out[(size_t)(b0 + bl) * S_TOT * 768 + h * 64 + lane] = o;
        }
        return;
    }

    // ================= loc role (R13 body) =================
    int xcd = dd & 7, kk_ = dd >> 3;
    int slot = xcd * (ng << 2) + kk_;      // ng*4 = total/8 blocks per XCD
    int g = slot >> 5;                      // group = h + 12*bl
    int m = slot & 31;
    int h = g % 12;
    int bl = g / 12;

    size_t base = (size_t)((bl * 12 + h) * S_TOT) * 64;
    const float* Qb = Q + base;
    const float* Kb = K + base;
    const float* Vb = V + base;

    // stage token table (295 entries, pad to 320 with token 0)
    for (int jj = tid; jj < 320; jj += 256) {
        int t = 0;
        if (jj >= 1 && jj < 295) {
            int j1 = jj - 1;
            int n = j1 / 49;
            int q = j1 - n * 49;
            int a;
            if (n == 0)      a = (m + 31) & 31;
            else if (n == 1) a = m;
            else if (n == 2) a = (m + 1) & 31;
            else             a = rand_idx[m * 3 + (n - 3)];
            t = 1 + a * 49 + q;
        }
        sm.loc.tok[jj] = (unsigned short)t;
    }
    // stage per-row packed query coords: cq = zq*729 + yq*27 + xq
    if (tid < 52) {
        int qr = 1 + m * 49 + tid;
        if (qr > S_TOT - 1) qr = S_TOT - 1;
        int pq = qr - 1;
        int zq = pq / 196;
        int rem = pq - zq * 196;
        int yq = rem / 14;
        int xq = rem - yq * 14;
        sm.loc.cqlds[tid] = zq * 729 + yq * 27 + xq;
    }
    // stage Q tile (49 rows), coalesced
    for (int idx = tid; idx < 49 * 64; idx += 256) {
        int r = idx >> 6, c = idx & 63;
        ((float*)sm.loc.Qlds)[idx] = Qb[(size_t)(1 + m * 49 + r) * 64 + c];
    }
    __syncthreads();

    float facc[13];
#pragma unroll
    for (int r = 0; r < 13; r++) facc[r] = 0.f;

    for (int jc = 0; jc < 5; jc++) {
        int j = jc * 64 + lane;
        int tj = sm.loc.tok[j];
        const float* kp = Kb + (size_t)tj * 64;

        // per-lane key coords -> bias offset  bidx = cq[i] + cjb
        int pj = tj - 1;
        int zj = pj / 196;
        int remj = pj - zj * 196;
        int yj = remj / 14;
        int xj = remj - yj * 14;
        int cjb = 5467 - (zj * 729 + yj * 27 + xj);
        bool iscls = (tj == 0);
        bool jv = j < 295;

        // ---- QK^T + bias + exp + sum, two row-passes (s[] stays 7 wide)
#pragma unroll
        for (int half = 0; half < 2; half++) {
            const int r0 = half * 7;
            const int RN = half ? 6 : 7;
            float s[7];
#pragma unroll
            for (int rr = 0; rr < 7; rr++) s[rr] = 0.f;
#pragma unroll 4
            for (int d4 = 0; d4 < 16; d4++) {
                float4 kv = *(const float4*)(kp + d4 * 4);
#pragma unroll
                for (int rr = 0; rr < RN; rr++) {
                    int qrow = w + 4 * (r0 + rr);
                    if (qrow > 48) qrow = 48;       // pad rows (unused lanes)
                    float4 qv = *(const float4*)&sm.loc.Qlds[qrow][d4 * 4];
                    s[rr] = fmaf(qv.x, kv.x, s[rr]);
                    s[rr] = fmaf(qv.y, kv.y, s[rr]);
                    s[rr] = fmaf(qv.z, kv.z, s[rr]);
                    s[rr] = fmaf(qv.w, kv.w, s[rr]);
                }
            }
#pragma unroll
            for (int rr = 0; rr < RN; rr++) {
                int r = r0 + rr;
                int i = w + 4 * r;
                int ii = (i > 48) ? 48 : i;
                int bidx = iscls ? 10936 : (sm.loc.cqlds[ii] + cjb);
                float e = jv ? __expf(fmaf(s[rr], 0.125f, rel[bidx * 12 + h])) : 0.f;
                float ps = e;
#pragma unroll
                for (int off = 32; off > 0; off >>= 1) ps += __shfl_xor(ps, off);
                if (lane == 0) sm.loc.flds[w][r][jc] = ps;
                sm.loc.Plds[w][r][lane] = e;
            }
        }

        // ---- PV for this chunk: 4 keys per step, P via b128 broadcast
#pragma unroll 4
        for (int jg = 0; jg < 16; jg++) {
            int jb = jc * 64 + jg * 4;
            int t0 = sm.loc.tok[jb + 0], t1 = sm.loc.tok[jb + 1];
            int t2 = sm.loc.tok[jb + 2], t3 = sm.loc.tok[jb + 3];
            float v0 = Vb[(size_t)t0 * 64 + lane];
            float v1 = Vb[(size_t)t1 * 64 + lane];
            float v2 = Vb[(size_t)t2 * 64 + lane];
            float v3 = Vb[(size_t)t3 * 64 + lane];
#pragma unroll
            for (int r = 0; r < 13; r++) {
                float4 p4 = *(const float4*)&sm.loc.Plds[w][r][jg * 4];  // broadcast
                facc[r] = fmaf(p4.x, v0, facc[r]);
                facc[r] = fmaf(p4.y, v1, facc[r]);
                facc[r] = fmaf(p4.z, v2, facc[r]);
                facc[r] = fmaf(p4.w, v3, facc[r]);
            }
        }
    }

    // ---- epilogue: normalize (fl = sum of per-chunk partials) and store
    int nrows = (w == 0) ? 13 : 12;
    for (int r = 0; r < nrows; r++) {
        float fl = ((sm.loc.flds[w][r][0] + sm.loc.flds[w][r][1]) +
                    (sm.loc.flds[w][r][2] + sm.loc.flds[w][r][3]))
                 + sm.loc.flds[w][r][4];
        int i = w + 4 * r;
        int st = 1 + m * 49 + i;
        out[((size_t)(b0 + bl) * S_TOT + st) * 768 + h * 64 + lane] = facc[r] / fl;
    }
}

extern "C" void kernel_launch(void* const* d_in, const int* in_sizes, int n_in,
                              void* d_out, int out_size, void* d_ws, size_t ws_size,
                              hipStream_t stream) {
    (void)in_sizes; (void)n_in; (void)out_size;
    const float* hs  = (const float*)d_in[0];
    const float* Wq  = (const float*)d_in[1];
    const float* bq  = (const float*)d_in[2];
    const float* Wk  = (const float*)d_in[3];
    const float* Wv  = (const float*)d_in[4];
    const float* bv  = (const float*)d_in[5];
    const float* rel = (const float*)d_in[6];
    const int*   rpi = (const int*)d_in[7];
    const int*   rnd = (const int*)d_in[8];
    float* out = (float*)d_out;
    char* ws = (char*)d_ws;

    // ws layout: Q | K | V  (each C * PBUF bytes)
    constexpr size_t PBUF = (size_t)12 * S_TOT * 64 * 4;     // 4,819,968 per batch

    int C = 1;
    if (ws_size >= 3 * PBUF) {
        size_t c = ws_size / (3 * PBUF);
        C = (c >= NBATCH) ? NBATCH : (int)c;
        if (C < 1) C = 1;
    }
    float* Q = (float*)(ws);
    float* K = (float*)(ws + (size_t)C * PBUF);
    float* V = (float*)(ws + (size_t)C * PBUF * 2);

    for (int b0 = 0; b0 < NBATCH; b0 += C) {
        int cb = (NBATCH - b0 < C) ? (NBATCH - b0) : C;
        int nTok = cb * S_TOT;
        int ntiles = ((nTok + 127) / 128) * 18;
        int gsz = (ntiles < 1536) ? ntiles : 1536;
        gemm_f32<<<dim3(gsz), dim3(256), 0, stream>>>(
            hs, Wq, Wk, Wv, bq, bv, Q, K, V, b0, nTok);
        int ngrp = 12 * cb;
        attn_fused<<<dim3(33 * ngrp), dim3(256), 0, stream>>>(
            Q, K, V, rel, rpi, rnd, out, b0, ngrp);
    }
}